// Round 11
// baseline (208.504 us; speedup 1.0000x reference)
//
#include <hip/hip_runtime.h>
#include <math.h>

typedef __attribute__((ext_vector_type(4))) float  f32x4;
typedef __attribute__((ext_vector_type(8))) short  s16x8;
typedef __attribute__((ext_vector_type(4))) short  s16x4;

#define BN_EPS 1e-3f

static constexpr int    CC    = 256;
static constexpr int    NVOX  = 32768;
static constexpr int    BATCH = 2;
static constexpr int    MTOT  = BATCH * NVOX;              // 65536 rows
static constexpr size_t ELEM_BR = (size_t)MTOT * CC;       // 16,777,216 per branch
static constexpr size_t SZ_BR   = ELEM_BR * 2;             // bf16 bytes
// workspace layout
static constexpr size_t WS_Q   = 0;
static constexpr size_t WS_K   = WS_Q  + SZ_BR;
static constexpr size_t WS_J   = WS_K  + SZ_BR;
static constexpr size_t WS_V   = WS_J  + SZ_BR;
static constexpr size_t WS_M1  = WS_V  + SZ_BR;                       // f32 [2][256][256]
static constexpr size_t WS_M2  = WS_M1 + (size_t)BATCH*CC*CC*4;
static constexpr size_t WS_AFF = WS_M2 + (size_t)BATCH*CC*CC*4;       // bf16 [2][256][256]
static constexpr size_t WS_WT  = WS_AFF + (size_t)BATCH*CC*CC*2;      // bf16 Wt[4][cout][cin]
static constexpr size_t WS_AB  = WS_WT + (size_t)4*CC*CC*2;           // f32 alpha[1024], beta[1024]
static constexpr size_t WS_P   = WS_AB + 2048*4;                      // bf16 partials [4][64][65536]
static constexpr size_t WS_NEED_PART = WS_P + (size_t)4*64*65536*2;   // ~162 MiB

__device__ __forceinline__ short f2bf(float f) {
  union { float f; unsigned u; } v; v.f = f;
  unsigned u = v.u + 0x7FFFu + ((v.u >> 16) & 1u);   // RNE
  return (short)(u >> 16);
}
__device__ __forceinline__ float bf2f(short s) {
  union { unsigned u; float f; } v; v.u = ((unsigned)(unsigned short)s) << 16;
  return v.f;
}
__device__ __forceinline__ unsigned long long packBN(f32x4 a, f32x4 al, f32x4 be) {
  union { s16x4 v; unsigned long long u; } c;
  #pragma unroll
  for (int ii = 0; ii < 4; ++ii) {
    float yv = al[ii] * a[ii] + be[ii];
    c.v[ii] = f2bf(yv > 0.f ? yv : 0.f);
  }
  return c.u;
}

// ---------------- k0: prep — transpose weights to bf16, fold BN, zero m1/m2 ----
__global__ __launch_bounds__(256) void k0_prep(
    const float* __restrict__ conv_w, const float* __restrict__ conv_b,
    const float* __restrict__ bn_s, const float* __restrict__ bn_o,
    const float* __restrict__ bn_m, const float* __restrict__ bn_v,
    char* __restrict__ ws)
{
  int t = blockIdx.x * 256 + threadIdx.x;              // 0..262143
  ((float*)(ws + WS_M1))[t] = 0.f;                     // zero m1+m2 (2*2*65536 f32)
  int f = t >> 16, rem = t & 65535;
  int cin = rem >> 8, cout = rem & 255;
  ((short*)(ws + WS_WT))[f*65536 + cout*256 + cin] = f2bf(conv_w[t]);
  if (t < 1024) {
    float alpha = bn_s[t] * rsqrtf(bn_v[t] + BN_EPS);
    float beta  = alpha * (conv_b[t] - bn_m[t]) + bn_o[t];
    float* ab = (float*)(ws + WS_AB);
    ab[t] = alpha; ab[1024 + t] = beta;
  }
}

// ---------------- k1: 4 fused conv+BN+ReLU branches (k2-shaped) ----------------
// 512 threads, 128 rows/block, 16 nt-tiles (4 branches x 4 cout-64-tiles).
// As 64KB staged once (swizzle u^(r&7)); A-frags in 16 NAMED regs read from
// LDS after the barrier (benign fallback: LDS re-read). Bs dbuf 2x32KB via
// global_load_lds, inverse-swizzled source. ONE barrier per nt. No Rs:
// shfl_xor(16) pairs lanes into 16B chunks -> 64B-contiguous row segments.
__global__ __launch_bounds__(512, 1) void k1_branches(
    const float* __restrict__ x, char* __restrict__ ws)
{
  __shared__ short As[128 * 256];      // 64KB
  __shared__ short Bs[2][64 * 256];    // 2 x 32KB

  const int tid = threadIdx.x;
  const int m0  = blockIdx.x * 128;
  const int lane = tid & 63, wid = tid >> 6;
  const int rowg = wid >> 1, coutg = wid & 1;   // 4 row-groups x 2 cout-groups
  const int lr = lane & 15, lg = lane >> 4;

  const short* Wt = (const short*)(ws + WS_WT);
  const float* ab = (const float*)(ws + WS_AB);

  // ---- issue Bs stage for nt=0 (DMA overlaps A staging)
  #pragma unroll
  for (int i = 0; i < 4; ++i) {
    int slot = i * 512 + tid;                  // 2048 16B slots
    int cout = slot >> 5, u = slot & 31;
    int usrc = u ^ (cout & 7);
    __builtin_amdgcn_global_load_lds(
        (const __attribute__((address_space(1))) void*)(Wt + cout * 256 + usrc * 8),
        (__attribute__((address_space(3))) void*)(&Bs[0][(i * 512 + wid * 64) * 8]),
        16, 0, 0);
  }

  // ---- stage As: 128x256 f32 -> bf16, swizzle u ^= (r&7)
  #pragma unroll
  for (int it = 0; it < 16; ++it) {
    int idx = tid + 512 * it;                  // 8192 float4 units
    int r = idx >> 6, c4 = (idx & 63) << 2;
    const float4 v = *(const float4*)(x + (size_t)(m0 + r) * 256 + c4);
    s16x4 s; s[0]=f2bf(v.x); s[1]=f2bf(v.y); s[2]=f2bf(v.z); s[3]=f2bf(v.w);
    int u = c4 >> 3;
    int swz = ((u ^ (r & 7)) << 3) | (c4 & 7);
    *(s16x4*)&As[r * 256 + swz] = s;
  }

  __syncthreads();                             // As + Bs(0) ready

  // ---- A fragments -> 16 named registers (LDS-sourced; conflict-free 2-way)
  const int rA0 = rowg * 32 + lr, rA1 = rA0 + 16;
#define LDA(R, K) (*(const s16x8*)&As[(R) * 256 + ((((K)*4 + lg) ^ ((R) & 7)) * 8)])
  const s16x8 fa00 = LDA(rA0,0), fa01 = LDA(rA0,1), fa02 = LDA(rA0,2), fa03 = LDA(rA0,3);
  const s16x8 fa04 = LDA(rA0,4), fa05 = LDA(rA0,5), fa06 = LDA(rA0,6), fa07 = LDA(rA0,7);
  const s16x8 fa10 = LDA(rA1,0), fa11 = LDA(rA1,1), fa12 = LDA(rA1,2), fa13 = LDA(rA1,3);
  const s16x8 fa14 = LDA(rA1,4), fa15 = LDA(rA1,5), fa16 = LDA(rA1,6), fa17 = LDA(rA1,7);
#undef LDA

  const int cB0 = coutg * 32 + lr, cB1 = cB0 + 16;

  for (int nt = 0; nt < 16; ++nt) {
    const int f  = nt >> 2;
    const int c0 = (nt & 3) * 64;

    // ---- issue next tile's stage into the other buffer
    if (nt < 15) {
      const int ntn = nt + 1;
      const short* Wf = Wt + (ntn >> 2) * 65536 + ((ntn & 3) * 64) * 256;
      short* Bn = Bs[ntn & 1];
      #pragma unroll
      for (int i = 0; i < 4; ++i) {
        int slot = i * 512 + tid;
        int cout = slot >> 5, u = slot & 31;
        int usrc = u ^ (cout & 7);
        __builtin_amdgcn_global_load_lds(
            (const __attribute__((address_space(1))) void*)(Wf + cout * 256 + usrc * 8),
            (__attribute__((address_space(3))) void*)(&Bn[(i * 512 + wid * 64) * 8]),
            16, 0, 0);
      }
    }

    // ---- k-loop: 2 B ds_reads + 4 MFMA per step, A from regs, no barriers
    const short* Bc = Bs[nt & 1];
    f32x4 acc00 = {0.f,0.f,0.f,0.f}, acc01 = {0.f,0.f,0.f,0.f};
    f32x4 acc10 = {0.f,0.f,0.f,0.f}, acc11 = {0.f,0.f,0.f,0.f};
#define KST(K, A0, A1) { \
    const int ua_ = (K) * 4 + lg; \
    const s16x8 b0_ = *(const s16x8*)&Bc[cB0 * 256 + ((ua_ ^ (cB0 & 7)) * 8)]; \
    const s16x8 b1_ = *(const s16x8*)&Bc[cB1 * 256 + ((ua_ ^ (cB1 & 7)) * 8)]; \
    acc00 = __builtin_amdgcn_mfma_f32_16x16x32_bf16(b0_, (A0), acc00, 0,0,0); \
    acc01 = __builtin_amdgcn_mfma_f32_16x16x32_bf16(b1_, (A0), acc01, 0,0,0); \
    acc10 = __builtin_amdgcn_mfma_f32_16x16x32_bf16(b0_, (A1), acc10, 0,0,0); \
    acc11 = __builtin_amdgcn_mfma_f32_16x16x32_bf16(b1_, (A1), acc11, 0,0,0); }
    KST(0, fa00, fa10) KST(1, fa01, fa11) KST(2, fa02, fa12) KST(3, fa03, fa13)
    KST(4, fa04, fa14) KST(5, fa05, fa15) KST(6, fa06, fa16) KST(7, fa07, fa17)
#undef KST

    // ---- epilogue: BN+ReLU -> pack -> shfl_xor(16) -> 16B stores (64B/row segs)
    // mapping: row m = m0 + rowg*32 + mi*16 + lr; cout = c0 + coutg*32 + nj*16 + lg*4+ii
    short* Yf = (short*)(ws + (size_t)f * SZ_BR);
    {
      const int cbase = c0 + coutg * 32;
      const f32x4 al0 = *(const f32x4*)&ab[f*256 + cbase + lg*4];
      const f32x4 be0 = *(const f32x4*)&ab[1024 + f*256 + cbase + lg*4];
      const f32x4 al1 = *(const f32x4*)&ab[f*256 + cbase + 16 + lg*4];
      const f32x4 be1 = *(const f32x4*)&ab[1024 + f*256 + cbase + 16 + lg*4];
      const int cout_s = cbase + (lg & 1) * 16 + (lg >> 1) * 8;
      // mi = 0
      {
        unsigned long long p0 = packBN(acc00, al0, be0);
        unsigned long long p1 = packBN(acc01, al1, be1);
        unsigned long long q0 = __shfl_xor(p0, 16, 64);
        unsigned long long q1 = __shfl_xor(p1, 16, 64);
        ulonglong2 ch0, ch1;
        if (lg & 1) { ch0.x = q0; ch0.y = p0; ch1.x = q1; ch1.y = p1; }
        else        { ch0.x = p0; ch0.y = q0; ch1.x = p1; ch1.y = q1; }
        ulonglong2 sel = (lg & 1) ? ch1 : ch0;
        *(ulonglong2*)&Yf[(size_t)(m0 + rowg*32 + lr) * 256 + cout_s] = sel;
      }
      // mi = 1
      {
        unsigned long long p0 = packBN(acc10, al0, be0);
        unsigned long long p1 = packBN(acc11, al1, be1);
        unsigned long long q0 = __shfl_xor(p0, 16, 64);
        unsigned long long q1 = __shfl_xor(p1, 16, 64);
        ulonglong2 ch0, ch1;
        if (lg & 1) { ch0.x = q0; ch0.y = p0; ch1.x = q1; ch1.y = p1; }
        else        { ch0.x = p0; ch0.y = q0; ch1.x = p1; ch1.y = q1; }
        ulonglong2 sel = (lg & 1) ? ch1 : ch0;
        *(ulonglong2*)&Yf[(size_t)(m0 + rowg*32 + 16 + lr) * 256 + cout_s] = sel;
      }
    }

    __syncthreads();   // drains stage(nt+1); guards Bs buffer reuse
  }
}

// ---------------- k2: m1 = K*Q^T, m2 = K*J^T ---------------------------------
template<int PART>
__global__ __launch_bounds__(512, 2) void k2_m1m2(char* __restrict__ ws)
{
  __shared__ short Ks[2][16384];   // [buf][256 rows x 64 n] 32KB each
  __shared__ short Xs[2][16384];

  const int tid = threadIdx.x;               // 0..511
  const int chunk = blockIdx.x;              // 64 chunks x 512 voxels
  const int mat = blockIdx.y;                // 0: m1 (X=Q), 1: m2 (X=J)
  const int b   = blockIdx.z;
  const size_t boff = (size_t)b * NVOX * CC;
  const short* Km = (const short*)(ws + WS_K) + boff;
  const short* Xm = (const short*)(ws + (mat ? WS_J : WS_Q)) + boff;

  const int lane = tid & 63, wid = tid >> 6;
  const int wm = wid >> 1, wn = wid & 1;     // 4 m-tiles(64 rows) x 2 n-tiles(128 cols)
  const int lr = lane & 15, lg = lane >> 4;

  f32x4 acc[4][8];
  #pragma unroll
  for (int a = 0; a < 4; ++a)
    #pragma unroll
    for (int c = 0; c < 8; ++c) { f32x4 z = {0.f,0.f,0.f,0.f}; acc[a][c] = z; }

  {
    const int n0 = chunk * 512;
    #pragma unroll
    for (int i = 0; i < 4; ++i) {
      int slot = i * 512 + tid;              // 2048 16B-units per matrix tile
      int r = slot >> 3, u = slot & 7;
      int usrc = u ^ (r & 7);
      const size_t so = (size_t)r * NVOX + n0 + usrc * 8;
      short* dK = Ks[0] + (size_t)(i * 512 + wid * 64) * 8;
      short* dX = Xs[0] + (size_t)(i * 512 + wid * 64) * 8;
      __builtin_amdgcn_global_load_lds(
          (const __attribute__((address_space(1))) void*)(Km + so),
          (__attribute__((address_space(3))) void*)dK, 16, 0, 0);
      __builtin_amdgcn_global_load_lds(
          (const __attribute__((address_space(1))) void*)(Xm + so),
          (__attribute__((address_space(3))) void*)dX, 16, 0, 0);
    }
  }
  __syncthreads();

  for (int t = 0; t < 8; ++t) {
    const int cur = t & 1;
    if (t < 7) {
      const int n0n = chunk * 512 + (t + 1) * 64;
      const int nxt = cur ^ 1;
      #pragma unroll
      for (int i = 0; i < 4; ++i) {
        int slot = i * 512 + tid;
        int r = slot >> 3, u = slot & 7;
        int usrc = u ^ (r & 7);
        const size_t so = (size_t)r * NVOX + n0n + usrc * 8;
        short* dK = Ks[nxt] + (size_t)(i * 512 + wid * 64) * 8;
        short* dX = Xs[nxt] + (size_t)(i * 512 + wid * 64) * 8;
        __builtin_amdgcn_global_load_lds(
            (const __attribute__((address_space(1))) void*)(Km + so),
            (__attribute__((address_space(3))) void*)dK, 16, 0, 0);
        __builtin_amdgcn_global_load_lds(
            (const __attribute__((address_space(1))) void*)(Xm + so),
            (__attribute__((address_space(3))) void*)dX, 16, 0, 0);
      }
    }
    #pragma unroll
    for (int ks = 0; ks < 2; ++ks) {
      const int ua = ks * 4 + lg;
      s16x8 a[4], xf[8];
      #pragma unroll
      for (int mi = 0; mi < 4; ++mi) {
        int r = wm*64 + mi*16 + lr;
        a[mi] = *(const s16x8*)&Ks[cur][r * 64 + (ua ^ (r & 7)) * 8];
      }
      #pragma unroll
      for (int nj = 0; nj < 8; ++nj) {
        int r = wn*128 + nj*16 + lr;
        xf[nj] = *(const s16x8*)&Xs[cur][r * 64 + (ua ^ (r & 7)) * 8];
      }
      #pragma unroll
      for (int mi = 0; mi < 4; ++mi)
        #pragma unroll
        for (int nj = 0; nj < 8; ++nj)
          acc[mi][nj] = __builtin_amdgcn_mfma_f32_16x16x32_bf16(
              a[mi], xf[nj], acc[mi][nj], 0, 0, 0);
    }
    __syncthreads();
  }

  if (PART) {
    short* P = (short*)(ws + WS_P) + ((size_t)((mat*2 + b)*64 + chunk)) * 65536;
    #pragma unroll
    for (int mi = 0; mi < 4; ++mi)
      #pragma unroll
      for (int nj = 0; nj < 8; ++nj) {
        int i = wm*64 + mi*16 + lg*4;
        int j = wn*128 + nj*16 + lr;
        #pragma unroll
        for (int ii = 0; ii < 4; ++ii)
          P[(size_t)(i + ii) * 256 + j] = f2bf(acc[mi][nj][ii]);
      }
  } else {
    float* M = (float*)(ws + (mat ? WS_M2 : WS_M1)) + (size_t)b * CC * CC;
    #pragma unroll
    for (int mi = 0; mi < 4; ++mi)
      #pragma unroll
      for (int nj = 0; nj < 8; ++nj) {
        int i = wm*64 + mi*16 + lg*4;
        int j = wn*128 + nj*16 + lr;
        #pragma unroll
        for (int ii = 0; ii < 4; ++ii)
          atomicAdd(&M[(size_t)(i + ii) * 256 + j], acc[mi][nj][ii]);
      }
  }
}

// ---------------- k25: reduce bf16 partials -> f32 m1/m2 ----------------------
__global__ __launch_bounds__(256) void k25_reduce(char* __restrict__ ws)
{
  int idx = blockIdx.x * 256 + threadIdx.x;   // 0..262143
  int mb = idx >> 16;                         // mat*2 + batch
  int ij = idx & 65535;
  const short* P = (const short*)(ws + WS_P) + ((size_t)mb * 64) * 65536 + ij;
  float s = 0.f;
  #pragma unroll 8
  for (int c = 0; c < 64; ++c)
    s += bf2f(P[(size_t)c * 65536]);
  float* dst = (float*)(ws + ((mb >> 1) ? WS_M2 : WS_M1)) + (size_t)(mb & 1) * 65536 + ij;
  *dst = s;
}

// ---------------- k3: affinity = sigmoid(m1 @ m2) -> bf16 ---------------------
__global__ __launch_bounds__(256) void k3_aff(char* __restrict__ ws)
{
  const int j = threadIdx.x;
  const int i = blockIdx.x & 255;
  const int b = blockIdx.x >> 8;
  const float* m1 = (const float*)(ws + WS_M1) + (size_t)b * CC * CC;
  const float* m2 = (const float*)(ws + WS_M2) + (size_t)b * CC * CC;
  float z = 0.f;
  #pragma unroll 8
  for (int k = 0; k < 256; ++k)
    z = fmaf(m1[i*256 + k], m2[k*256 + j], z);
  float a = 1.f / (1.f + expf(-z));
  ((short*)(ws + WS_AFF))[(size_t)b*CC*CC + i*256 + j] = f2bf(a);
}

// ---------------- k4: out = gamma * (affinity @ V) + x ------------------------
__global__ __launch_bounds__(512, 4) void k4_out(
    const float* __restrict__ x, const float* __restrict__ gamma_p,
    char* __restrict__ ws, float* __restrict__ out)
{
  __shared__ short affS[256][72];  // rows i, 64-c chunk
  __shared__ short Vs[128][72];    // rows n, 64-c chunk (transposed stage)

  const int tid = threadIdx.x;
  const int n0 = blockIdx.x * 128;
  const int b  = blockIdx.y;
  const float gamma = gamma_p[0];
  const short* aff = (const short*)(ws + WS_AFF) + (size_t)b * CC * CC;
  const short* Vm  = (const short*)(ws + WS_V) + (size_t)b * NVOX * CC;

  const int lane = tid & 63, wid = tid >> 6;
  const int wi = wid >> 1, wn = wid & 1;
  const int lr = lane & 15, lg = lane >> 4;

  f32x4 acc[4][4];
  #pragma unroll
  for (int a = 0; a < 4; ++a)
    #pragma unroll
    for (int c = 0; c < 4; ++c) { f32x4 z = {0.f,0.f,0.f,0.f}; acc[a][c] = z; }

  for (int c0 = 0; c0 < 256; c0 += 64) {
    __syncthreads();
    #pragma unroll
    for (int it = 0; it < 4; ++it) {
      int idx = tid + 512 * it;
      int r = idx >> 3, c8 = (idx & 7) << 3;
      *(s16x8*)&affS[r][c8] = *(const s16x8*)&aff[(size_t)r * 256 + c0 + c8];
    }
    #pragma unroll
    for (int it = 0; it < 2; ++it) {
      int idx = tid + 512 * it;
      int t15 = idx & 15;
      int cc = idx >> 4, n8 = t15 << 3;
      s16x8 v = *(const s16x8*)&Vm[(size_t)(c0 + cc) * NVOX + n0 + n8];
      #pragma unroll
      for (int uu = 0; uu < 8; ++uu) {
        int u = (uu + t15) & 7;
        Vs[n8 + u][cc] = v[u];
      }
    }
    __syncthreads();
    #pragma unroll
    for (int ks = 0; ks < 2; ++ks) {
      s16x8 af[4], bv[4];
      #pragma unroll
      for (int mi = 0; mi < 4; ++mi)
        af[mi] = *(const s16x8*)&affS[wi*64 + mi*16 + lr][ks*32 + lg*8];
      #pragma unroll
      for (int nj = 0; nj < 4; ++nj)
        bv[nj] = *(const s16x8*)&Vs[wn*64 + nj*16 + lr][ks*32 + lg*8];
      #pragma unroll
      for (int mi = 0; mi < 4; ++mi)
        #pragma unroll
        for (int nj = 0; nj < 4; ++nj)
          acc[mi][nj] = __builtin_amdgcn_mfma_f32_16x16x32_bf16(
              bv[nj], af[mi], acc[mi][nj], 0, 0, 0);   // D = V^T·aff^T
    }
  }
  #pragma unroll
  for (int mi = 0; mi < 4; ++mi)
    #pragma unroll
    for (int nj = 0; nj < 4; ++nj) {
      int i = wi*64 + mi*16 + lr;
      int n = n0 + wn*64 + nj*16 + lg*4;
      size_t flat = (size_t)b * NVOX * CC + (size_t)i * NVOX + n;
      const float4 xv = *(const float4*)(x + flat);
      float4 o;
      o.x = gamma * acc[mi][nj][0] + xv.x;
      o.y = gamma * acc[mi][nj][1] + xv.y;
      o.z = gamma * acc[mi][nj][2] + xv.z;
      o.w = gamma * acc[mi][nj][3] + xv.w;
      *(float4*)(out + flat) = o;
    }
}

// ---------------- launcher ----------------------------------------------------
extern "C" void kernel_launch(void* const* d_in, const int* in_sizes, int n_in,
                              void* d_out, int out_size, void* d_ws, size_t ws_size,
                              hipStream_t stream)
{
  const float* x      = (const float*)d_in[0];
  const float* conv_w = (const float*)d_in[1];
  const float* conv_b = (const float*)d_in[2];
  const float* bn_s   = (const float*)d_in[3];
  const float* bn_o   = (const float*)d_in[4];
  const float* bn_m   = (const float*)d_in[5];
  const float* bn_v   = (const float*)d_in[6];
  const float* gamma  = (const float*)d_in[7];
  char*  ws  = (char*)d_ws;
  float* out = (float*)d_out;

  const bool part = ws_size >= WS_NEED_PART;

  k0_prep    <<<1024, 256, 0, stream>>>(conv_w, conv_b, bn_s, bn_o, bn_m, bn_v, ws);
  k1_branches<<<512, 512, 0, stream>>>(x, ws);
  if (part) {
    k2_m1m2<1><<<dim3(64, 2, 2), 512, 0, stream>>>(ws);
    k25_reduce<<<1024, 256, 0, stream>>>(ws);
  } else {
    k2_m1m2<0><<<dim3(64, 2, 2), 512, 0, stream>>>(ws);
  }
  k3_aff     <<<512, 256, 0, stream>>>(ws);
  k4_out     <<<dim3(256, 2), 512, 0, stream>>>(x, gamma, ws, out);
}